// Round 19
// baseline (114.787 us; speedup 1.0000x reference)
//
#include <hip/hip_runtime.h>
#include <math.h>
#include <stdint.h>

#define T_TOTAL 2048
#define NB 16
#define D 256
#define T0 1696      // h buffer covers t in [1696, 2047]
#define TBUF 352
#define TSKIP 1952   // output rows t in [1952, 2047]
#define LOUT 96

typedef __bf16 bf16x8 __attribute__((ext_vector_type(8)));
typedef __bf16 bf16x4v __attribute__((ext_vector_type(4)));
typedef float f32x4 __attribute__((ext_vector_type(4)));

__device__ __forceinline__ void gload_lds16(const void* src, void* lds_dst) {
    auto g = (const __attribute__((address_space(1))) void*)(uintptr_t)src;
    auto l = (__attribute__((address_space(3))) void*)(uintptr_t)(
                 (uint32_t)(uintptr_t)lds_dst);
    __builtin_amdgcn_global_load_lds(g, l, 16, 0, 0);
}

// XCD-grouped decode over ngate blocks (ngate = mtp*8, mtp%8==0)
__device__ __forceinline__ void decode_tile(int id, int ngate, int& rt, int& ct) {
    int k = id & 7;
    int j = id >> 3;
    int rpx = ngate >> 6;
    rt = k * rpx + (j >> 3);
    ct = j & 7;
}

// ---------------- prep: wT, w2(ly0-4), w2T(ly5,6), up-projection(bf16 h), vW
__global__ __launch_bounds__(256) void prep_up(
    const float* __restrict__ dil_w, const float* __restrict__ skip_w,
    const float* __restrict__ x_lag, const float* __restrict__ x_cov,
    const float* __restrict__ up_W, const float* __restrict__ up_b,
    const float* __restrict__ loc_W,
    __bf16* __restrict__ wT, __bf16* __restrict__ w2, __bf16* __restrict__ w2T,
    __bf16* __restrict__ hb, float* __restrict__ vWp)
{
    const int g0 = blockIdx.x * 256 + threadIdx.x;
    const int NT = 2048 * 256;

    // job A: dil_w transpose -> wT[i][co][k], k = tap*256+ci
    for (int u = g0; u < 8 * 512 * 32; u += NT) {
        int j = u & 31;
        int cog = u >> 5;
        const float* src = dil_w + ((size_t)cog << 9) + (j << 4);
        float4 a = *(const float4*)(src);
        float4 b = *(const float4*)(src + 4);
        float4 c = *(const float4*)(src + 8);
        float4 d = *(const float4*)(src + 12);
        bf16x8 t0 = {(__bf16)a.x, (__bf16)a.z, (__bf16)b.x, (__bf16)b.z,
                     (__bf16)c.x, (__bf16)c.z, (__bf16)d.x, (__bf16)d.z};
        bf16x8 t1 = {(__bf16)a.y, (__bf16)a.w, (__bf16)b.y, (__bf16)b.w,
                     (__bf16)c.y, (__bf16)c.w, (__bf16)d.y, (__bf16)d.w};
        *(bf16x8*)(wT + ((size_t)cog << 9) + (j << 3)) = t0;
        *(bf16x8*)(wT + ((size_t)cog << 9) + 256 + (j << 3)) = t1;
    }
    // job B1: skip_w h-half cast -> w2[ly][co][ci], ly 0..4
    for (int u = g0; u < 5 * 256 * 32; u += NT) {
        int row = u >> 5, j = u & 31;             // row = ly*256+co
        int ly = row >> 8, co = row & 255;
        const float* src = skip_w + (((size_t)(ly << 9) + co) << 8) + (j << 3);
        float4 a = *(const float4*)(src);
        float4 b = *(const float4*)(src + 4);
        bf16x8 v = {(__bf16)a.x, (__bf16)a.y, (__bf16)a.z, (__bf16)a.w,
                    (__bf16)b.x, (__bf16)b.y, (__bf16)b.z, (__bf16)b.w};
        *(bf16x8*)(w2 + ((size_t)row << 8) + (j << 3)) = v;
    }
    // job B2: skip_w h-half transpose -> w2T[lyr][ci][co], lyr 0->ly5, 1->ly6
    for (int u = g0; u < 2 * 256 * 32; u += NT) {
        int row = u >> 5, j = u & 31;             // row = lyr*256+co
        int lyr = row >> 8, co = row & 255;
        int ly = 5 + lyr;
        const float* src = skip_w + (((size_t)(ly << 9) + co) << 8) + (j << 3);
        float4 a = *(const float4*)(src);
        float4 b = *(const float4*)(src + 4);
        float v[8] = {a.x, a.y, a.z, a.w, b.x, b.y, b.z, b.w};
        __bf16* wt = w2T + ((size_t)lyr << 16) + ((size_t)(j << 3) << 8) + co;
        #pragma unroll
        for (int e = 0; e < 8; ++e) wt[(size_t)e << 8] = (__bf16)v[e];
    }
    // job C: up-projection -> hb (bf16 accumulator master)
    for (int u = g0; u < TBUF * NB * D; u += NT) {
        int row = u >> 8, c = u & 255;
        int tt = row >> 4, b = row & 15, t = T0 + tt;
        float acc = up_b[c] + x_lag[t * NB + b] * up_W[c];
        const float* cov = &x_cov[(t * NB + b) * 7];
        #pragma unroll
        for (int j = 0; j < 7; ++j)
            acc += cov[j] * up_W[(j + 1) * D + c];
        hb[u] = (__bf16)acc;
    }
    // job D: vW partials over s-half skip_w (all 8 layers)
    for (int u = g0; u < 16384; u += NT) {
        int part = u >> 11;
        int r = u & 2047;
        int ly = r >> 8, ci = r & 255;
        const float* sw = skip_w + (((size_t)(ly << 9) + 256 + (part << 5)) << 8) + ci;
        float acc = 0.f;
        #pragma unroll 8
        for (int c = 0; c < 32; ++c)
            acc += sw[(size_t)c << 8] * loc_W[(part << 5) + c];
        vWp[u] = acc;
    }
}

// ---------------- D0: gate layer0 | V GEMMs (V65,V75,V76) | cbias6/7 folds
__global__ __launch_bounds__(512, 4) void d0_kernel(
    const __bf16* __restrict__ hb, __bf16* __restrict__ gated,
    const __bf16* __restrict__ wT, const float* __restrict__ dil_b,
    const __bf16* __restrict__ w2T, const float* __restrict__ skip_b,
    __bf16* __restrict__ V, float* __restrict__ cbias,
    __bf16* __restrict__ gsv, int ngate, int tb, int M)
{
    __shared__ __align__(16) unsigned char lds[32768];
    const int id = blockIdx.x;
    const int tid = threadIdx.x;
    const int lane = tid & 63, wid = tid >> 6;
    const int wm = wid >> 1, wn = wid & 1;
    const int l15 = lane & 15, l4 = lane >> 4;
    const int ach = lane & 7;

    if (id < ngate) {
        // ---- gate layer 0 (K=512, dil=1), save tail to gsv
        int rt, ct;
        decode_tile(id, ngate, rt, ct);
        const int m0 = rt << 6;
        if (m0 >= M) return;
        const int cb = ct << 5;
        const int arow = (wid << 3) + (lane >> 3);
        const int aswz = (ach ^ (arow & 7)) << 3;
        const int bwid = wid & 3, bhalf = wid >> 2;
        const int brow = (bwid << 3) + (lane >> 3);
        const int bswz = (ach ^ (brow & 7)) << 3;
        const int roff1 = (tb - T0) * 16;
        const int roff0 = roff1 - 16;

        f32x4 accf = {}, accg = {};
        auto stage = [&](int t, int buf) {
            const int k0 = t << 6;
            const int ci0 = k0 & 255;
            const int roff = (t < 4) ? roff0 : roff1;
            unsigned char* base = lds + buf * 16384;
            int m = m0 + arow; if (m >= M) m = M - 1;
            gload_lds16(hb + (size_t)(m + roff) * 256 + ci0 + aswz,
                        base + (wid << 10));
            gload_lds16(wT + (size_t)(cb + bhalf * 256 + brow) * 512 + k0 + bswz,
                        base + 8192 + (bhalf << 12) + (bwid << 10));
        };
        stage(0, 0);
        for (int t = 0; t < 8; ++t) {
            const int buf = t & 1;
            if (t < 7) {
                stage(t + 1, buf ^ 1);
                asm volatile("s_waitcnt vmcnt(2)" ::: "memory");
            } else {
                asm volatile("s_waitcnt vmcnt(0)" ::: "memory");
            }
            __builtin_amdgcn_s_barrier();
            const unsigned char* base = lds + buf * 16384;
            __builtin_amdgcn_s_setprio(1);
            #pragma unroll
            for (int ks = 0; ks < 2; ++ks) {
                const int kb = (ks << 6) + (l4 << 4);
                int r = (wm << 4) + l15;
                bf16x8 av = *(const bf16x8*)(base + r * 128 + (kb ^ ((r & 7) << 4)));
                int n = (wn << 4) + l15;
                int o = n * 128 + (kb ^ ((n & 7) << 4));
                bf16x8 bfv = *(const bf16x8*)(base + 8192 + o);
                bf16x8 bgv = *(const bf16x8*)(base + 12288 + o);
                accf = __builtin_amdgcn_mfma_f32_16x16x32_bf16(av, bfv, accf, 0, 0, 0);
                accg = __builtin_amdgcn_mfma_f32_16x16x32_bf16(av, bgv, accg, 0, 0, 0);
            }
            __builtin_amdgcn_s_setprio(0);
            __builtin_amdgcn_s_barrier();
        }
        {
            const int ms0 = (TSKIP - tb) * 16;
            const int soff = (tb - TSKIP) * 16;
            int c = cb + (wn << 4) + l15;
            float bfb = dil_b[c], bgb = dil_b[c + 256];
            #pragma unroll
            for (int r = 0; r < 4; ++r) {
                int m = m0 + (wm << 4) + (l4 << 2) + r;
                if (m < M) {
                    float fv = accf[r] + bfb;
                    float gv = accg[r] + bgb;
                    float th = 2.0f / (1.0f + __expf(-2.0f * fv)) - 1.0f;
                    float sg = 1.0f / (1.0f + __expf(-gv));
                    __bf16 val = (__bf16)(th * sg);
                    gated[(size_t)m * 256 + c] = val;
                    if (m >= ms0)
                        gsv[(size_t)(m + soff) * 256 + c] = val;
                }
            }
        }
    } else if (id < ngate + 384) {
        // ---- V GEMM role: pair 0=(tgt6,src ly5) 1=(7,ly5) 2=(7,ly6)
        int v = id - ngate;
        int pair = v >> 7;
        int r = v & 127;
        int tgt = (pair == 0) ? 6 : 7;
        int srcix = (pair == 2) ? 1 : 0;
        int a = r >> 6;
        int rt = (r & 63) >> 3, ct = r & 7;
        const int n0t = rt << 6;
        const int cb = ct << 5;
        const __bf16* Awt = wT + ((size_t)tgt << 18) + (a << 8);
        const __bf16* Bw = w2T + ((size_t)srcix << 16);
        const int arow = (wid << 3) + (lane >> 3);
        const int aswz = (ach ^ (arow & 7)) << 3;
        const int brow = (wid << 3) + (lane >> 3);
        const int bswz = (ach ^ (brow & 7)) << 3;

        f32x4 acc = {};
        auto stage = [&](int t, int buf) {
            const int k0 = t << 6;
            unsigned char* base = lds + buf * 12288;
            gload_lds16(Awt + (size_t)(n0t + arow) * 512 + k0 + aswz,
                        base + (wid << 10));
            if (wid < 4)
                gload_lds16(Bw + (size_t)(cb + brow) * 256 + k0 + bswz,
                            base + 8192 + (wid << 10));
        };
        stage(0, 0);
        for (int t = 0; t < 4; ++t) {
            const int buf = t & 1;
            if (t < 3) {
                stage(t + 1, buf ^ 1);
                if (wid < 4) { asm volatile("s_waitcnt vmcnt(2)" ::: "memory"); }
                else         { asm volatile("s_waitcnt vmcnt(1)" ::: "memory"); }
            } else {
                asm volatile("s_waitcnt vmcnt(0)" ::: "memory");
            }
            __builtin_amdgcn_s_barrier();
            const unsigned char* base = lds + buf * 12288;
            #pragma unroll
            for (int ks = 0; ks < 2; ++ks) {
                const int kb = (ks << 6) + (l4 << 4);
                int rr = (wm << 4) + l15;
                bf16x8 av = *(const bf16x8*)(base + rr * 128 + (kb ^ ((rr & 7) << 4)));
                int nn = (wn << 4) + l15;
                int o = nn * 128 + (kb ^ ((nn & 7) << 4));
                bf16x8 bv = *(const bf16x8*)(base + 8192 + o);
                acc = __builtin_amdgcn_mfma_f32_16x16x32_bf16(av, bv, acc, 0, 0, 0);
            }
            __builtin_amdgcn_s_barrier();
        }
        {
            int c = cb + (wn << 4) + l15;
            #pragma unroll
            for (int rr = 0; rr < 4; ++rr) {
                int n = n0t + (wm << 4) + (l4 << 2) + rr;
                V[((size_t)pair << 18) + (size_t)n * 512 + (a << 8) + c] = (__bf16)acc[rr];
            }
        }
    } else {
        // ---- cbias: tl=0 -> gate6 (fold sb5), tl=1 -> gate7 (sb5+sb6)
        int cblk = id - ngate - 384;              // 0..127
        int n = cblk * 8 + wid;                   // 0..1023
        int tl = n >> 9, n0 = n & 511;
        const __bf16* wrow = wT + ((size_t)(6 + tl) << 18) + ((size_t)n0 << 9);
        float s = 0.f;
        #pragma unroll
        for (int e = 0; e < 8; ++e) {
            int k = (lane << 3) + e;
            float sbv = skip_b[(5 << 9) + (k & 255)];
            if (tl == 1) sbv += skip_b[(6 << 9) + (k & 255)];
            s += sbv * (float)wrow[k];
        }
        #pragma unroll
        for (int off = 32; off; off >>= 1) s += __shfl_down(s, off);
        if (lane == 0)
            cbias[(tl << 9) + n0] = dil_b[((6 + tl) << 9) + n0] + s;
    }
}

// ---------------- GEMM1 narrow (layers 1..5): grid mtp*8, BN=32
__global__ __launch_bounds__(512, 4) void gate_n32(
    const __bf16* __restrict__ hb, __bf16* __restrict__ gout,
    const __bf16* __restrict__ wTl, const float* __restrict__ gbias,
    __bf16* __restrict__ gsv, int do_save,
    int tb, int dil, int M)
{
    __shared__ __align__(16) unsigned char lds[32768];
    int rt, ct;
    decode_tile(blockIdx.x, gridDim.x, rt, ct);
    const int m0 = rt << 6;
    if (m0 >= M) return;
    const int cb = ct << 5;
    const int tid = threadIdx.x;
    const int lane = tid & 63, wid = tid >> 6;
    const int wm = wid >> 1, wn = wid & 1;
    const int l15 = lane & 15, l4 = lane >> 4;
    const int arow = (wid << 3) + (lane >> 3);
    const int ach = lane & 7;
    const int aswz = (ach ^ (arow & 7)) << 3;
    const int bwid = wid & 3, bhalf = wid >> 2;
    const int brow = (bwid << 3) + (lane >> 3);
    const int bswz = (ach ^ (brow & 7)) << 3;
    const int roff1 = (tb - T0) * 16;
    const int roff0 = roff1 - dil * 16;

    f32x4 accf = {}, accg = {};
    auto stage = [&](int t, int buf) {
        const int k0 = t << 6;
        const int ci0 = k0 & 255;
        const int roff = (t < 4) ? roff0 : roff1;
        unsigned char* base = lds + buf * 16384;
        int m = m0 + arow; if (m >= M) m = M - 1;
        gload_lds16(hb + (size_t)(m + roff) * 256 + ci0 + aswz,
                    base + (wid << 10));
        gload_lds16(wTl + (size_t)(cb + bhalf * 256 + brow) * 512 + k0 + bswz,
                    base + 8192 + (bhalf << 12) + (bwid << 10));
    };
    stage(0, 0);
    for (int t = 0; t < 8; ++t) {
        const int buf = t & 1;
        if (t < 7) {
            stage(t + 1, buf ^ 1);
            asm volatile("s_waitcnt vmcnt(2)" ::: "memory");
        } else {
            asm volatile("s_waitcnt vmcnt(0)" ::: "memory");
        }
        __builtin_amdgcn_s_barrier();
        const unsigned char* base = lds + buf * 16384;
        __builtin_amdgcn_s_setprio(1);
        #pragma unroll
        for (int ks = 0; ks < 2; ++ks) {
            const int kb = (ks << 6) + (l4 << 4);
            int r = (wm << 4) + l15;
            bf16x8 av = *(const bf16x8*)(base + r * 128 + (kb ^ ((r & 7) << 4)));
            int n = (wn << 4) + l15;
            int o = n * 128 + (kb ^ ((n & 7) << 4));
            bf16x8 bfv = *(const bf16x8*)(base + 8192 + o);
            bf16x8 bgv = *(const bf16x8*)(base + 12288 + o);
            accf = __builtin_amdgcn_mfma_f32_16x16x32_bf16(av, bfv, accf, 0, 0, 0);
            accg = __builtin_amdgcn_mfma_f32_16x16x32_bf16(av, bgv, accg, 0, 0, 0);
        }
        __builtin_amdgcn_s_setprio(0);
        __builtin_amdgcn_s_barrier();
    }
    {
        const int ms0 = (TSKIP - tb) * 16;
        const int soff = (tb - TSKIP) * 16;
        int c = cb + (wn << 4) + l15;
        float bfb = gbias[c], bgb = gbias[c + 256];
        #pragma unroll
        for (int r = 0; r < 4; ++r) {
            int m = m0 + (wm << 4) + (l4 << 2) + r;
            if (m < M) {
                float fv = accf[r] + bfb;
                float gv = accg[r] + bgb;
                float th = 2.0f / (1.0f + __expf(-2.0f * fv)) - 1.0f;
                float sg = 1.0f / (1.0f + __expf(-gv));
                __bf16 val = (__bf16)(th * sg);
                gout[(size_t)m * 256 + c] = val;
                if (do_save && m >= ms0)
                    gsv[(size_t)(m + soff) * 256 + c] = val;
            }
        }
    }
}

// ---------------- substituted gate (compile-time unrolled): K = NSTEPS*64
template<int NSTEPS, int HRO0, int HRO1, int G1O0, int G1O1, int G2O0, int G2O1>
__global__ __launch_bounds__(512, 4) void gate_sub(
    const __bf16* __restrict__ hb,
    const __bf16* __restrict__ g1, const __bf16* __restrict__ g2,
    __bf16* __restrict__ gout,
    const __bf16* __restrict__ Bh, const __bf16* __restrict__ Bv1,
    const __bf16* __restrict__ Bv2, const float* __restrict__ cbias_l, int M)
{
    __shared__ __align__(16) unsigned char lds[32768];
    int rt, ct;
    decode_tile(blockIdx.x, gridDim.x, rt, ct);
    const int m0 = rt << 6;
    if (m0 >= M) return;
    const int cb = ct << 5;
    const int tid = threadIdx.x;
    const int lane = tid & 63, wid = tid >> 6;
    const int wm = wid >> 1, wn = wid & 1;
    const int l15 = lane & 15, l4 = lane >> 4;
    const int arow = (wid << 3) + (lane >> 3);
    const int ach = lane & 7;
    const int aswz = (ach ^ (arow & 7)) << 3;
    const int bwid = wid & 3, bhalf = wid >> 2;
    const int brow = (bwid << 3) + (lane >> 3);
    const int bswz = (ach ^ (brow & 7)) << 3;

    f32x4 accf = {}, accg = {};
    auto stage = [&](int t, int buf) {
        unsigned char* base = lds + buf * 16384;
        int m = m0 + arow; if (m >= M) m = M - 1;
        const __bf16* asrc;
        const __bf16* bsrc;
        int ks;
        if (t < 8) {
            ks = t << 6;
            asrc = hb + (size_t)(m + ((t < 4) ? HRO0 : HRO1)) * 256 + (ks & 255);
            bsrc = Bh;
        } else if (t < 16) {
            ks = (t - 8) << 6;
            asrc = g1 + (size_t)(m + ((t < 12) ? G1O0 : G1O1)) * 256 + (ks & 255);
            bsrc = Bv1;
        } else {
            ks = (t - 16) << 6;
            asrc = g2 + (size_t)(m + ((t < 20) ? G2O0 : G2O1)) * 256 + (ks & 255);
            bsrc = Bv2;
        }
        gload_lds16(asrc + aswz, base + (wid << 10));
        gload_lds16(bsrc + (size_t)(cb + bhalf * 256 + brow) * 512 + ks + bswz,
                    base + 8192 + (bhalf << 12) + (bwid << 10));
    };
    stage(0, 0);
    #pragma unroll
    for (int t = 0; t < NSTEPS; ++t) {
        const int buf = t & 1;
        if (t < NSTEPS - 1) {
            stage(t + 1, buf ^ 1);
            asm volatile("s_waitcnt vmcnt(2)" ::: "memory");
        } else {
            asm volatile("s_waitcnt vmcnt(0)" ::: "memory");
        }
        __builtin_amdgcn_s_barrier();
        const unsigned char* base = lds + buf * 16384;
        __builtin_amdgcn_s_setprio(1);
        #pragma unroll
        for (int ks = 0; ks < 2; ++ks) {
            const int kb = (ks << 6) + (l4 << 4);
            int r = (wm << 4) + l15;
            bf16x8 av = *(const bf16x8*)(base + r * 128 + (kb ^ ((r & 7) << 4)));
            int n = (wn << 4) + l15;
            int o = n * 128 + (kb ^ ((n & 7) << 4));
            bf16x8 bfv = *(const bf16x8*)(base + 8192 + o);
            bf16x8 bgv = *(const bf16x8*)(base + 12288 + o);
            accf = __builtin_amdgcn_mfma_f32_16x16x32_bf16(av, bfv, accf, 0, 0, 0);
            accg = __builtin_amdgcn_mfma_f32_16x16x32_bf16(av, bgv, accg, 0, 0, 0);
        }
        __builtin_amdgcn_s_setprio(0);
        __builtin_amdgcn_s_barrier();
    }
    {
        int c = cb + (wn << 4) + l15;
        float bfb = cbias_l[c], bgb = cbias_l[c + 256];
        #pragma unroll
        for (int r = 0; r < 4; ++r) {
            int m = m0 + (wm << 4) + (l4 << 2) + r;
            if (m < M) {
                float fv = accf[r] + bfb;
                float gv = accg[r] + bgb;
                float th = 2.0f / (1.0f + __expf(-2.0f * fv)) - 1.0f;
                float sg = 1.0f / (1.0f + __expf(-gv));
                gout[(size_t)m * 256 + c] = (__bf16)(th * sg);
            }
        }
    }
}

// ---------------- GEMM2 h-only (layers 0..4): bf16 in-place h accumulate
__global__ __launch_bounds__(512, 4) void skip_h(
    const __bf16* __restrict__ gated, const __bf16* __restrict__ w2l,
    __bf16* __restrict__ hb, const float* __restrict__ sbias, int tb, int M)
{
    __shared__ __align__(16) unsigned char lds[24576];
    int rt, ct;
    decode_tile(blockIdx.x, gridDim.x, rt, ct);
    const int m0 = rt << 6;
    if (m0 >= M) return;
    const int cb = ct << 5;
    const int tid = threadIdx.x;
    const int lane = tid & 63, wid = tid >> 6;
    const int wm = wid >> 1, wn = wid & 1;
    const int l15 = lane & 15, l4 = lane >> 4;
    const int arow = (wid << 3) + (lane >> 3);
    const int ach = lane & 7;
    const int aswz = (ach ^ (arow & 7)) << 3;
    const int brow = (wid << 3) + (lane >> 3);
    const int bswz = (ach ^ (brow & 7)) << 3;
    const int roff1 = (tb - T0) * 16;

    f32x4 acch = {};
    auto stage = [&](int t, int buf) {
        const int k0 = t << 6;
        unsigned char* base = lds + buf * 12288;
        int m = m0 + arow; if (m >= M) m = M - 1;
        gload_lds16(gated + (size_t)m * 256 + k0 + aswz,
                    base + (wid << 10));
        if (wid < 4)
            gload_lds16(w2l + (size_t)(cb + brow) * 256 + k0 + bswz,
                        base + 8192 + (wid << 10));
    };
    stage(0, 0);
    for (int t = 0; t < 4; ++t) {
        const int buf = t & 1;
        if (t < 3) {
            stage(t + 1, buf ^ 1);
            if (wid < 4) { asm volatile("s_waitcnt vmcnt(2)" ::: "memory"); }
            else         { asm volatile("s_waitcnt vmcnt(1)" ::: "memory"); }
        } else {
            asm volatile("s_waitcnt vmcnt(0)" ::: "memory");
        }
        __builtin_amdgcn_s_barrier();
        const unsigned char* base = lds + buf * 12288;
        __builtin_amdgcn_s_setprio(1);
        #pragma unroll
        for (int ks = 0; ks < 2; ++ks) {
            const int kb = (ks << 6) + (l4 << 4);
            int r = (wm << 4) + l15;
            bf16x8 av = *(const bf16x8*)(base + r * 128 + (kb ^ ((r & 7) << 4)));
            int n = (wn << 4) + l15;
            int o = n * 128 + (kb ^ ((n & 7) << 4));
            bf16x8 bhv = *(const bf16x8*)(base + 8192 + o);
            acch = __builtin_amdgcn_mfma_f32_16x16x32_bf16(av, bhv, acch, 0, 0, 0);
        }
        __builtin_amdgcn_s_setprio(0);
        __builtin_amdgcn_s_barrier();
    }
    {
        int c = cb + (wn << 4) + l15;
        float bhb = sbias[c];
        #pragma unroll
        for (int r = 0; r < 4; ++r) {
            int m = m0 + (wm << 4) + (l4 << 2) + r;
            if (m < M) {
                size_t hi = (size_t)(m + roff1) * 256 + c;
                float hv = (float)hb[hi] + acch[r] + bhb;
                hb[hi] = (__bf16)hv;
            }
        }
    }
}

// ---------------- final
__global__ __launch_bounds__(256) void final_v6(
    const __bf16* __restrict__ gsave, const __bf16* __restrict__ gA,
    const __bf16* __restrict__ gB, const __bf16* __restrict__ g7,
    const float* __restrict__ vWp, const float* __restrict__ skip_b,
    const float* __restrict__ loc_W, const float* __restrict__ loc_b,
    const float* __restrict__ proj_W, const float* __restrict__ proj_b,
    float* __restrict__ out)
{
    int tid = threadIdx.x;
    int wid = tid >> 6, lane = tid & 63;
    int o = blockIdx.x * 4 + wid;        // o = (t - TSKIP)*16 + b
    const __bf16* bases[8] = {
        gsave,                  gsave + 1536 * 256,     gsave + 2 * 1536 * 256,
        gsave + 3 * 1536 * 256, gsave + 4 * 1536 * 256,
        gA + 3072 * 256,        gB + 2048 * 256,        g7 };
    float acc = 0.f;
    #pragma unroll
    for (int ly = 0; ly < 8; ++ly) {
        bf16x4v gv = *(const bf16x4v*)(bases[ly] + ((size_t)o << 8) + (lane << 2));
        float4 vw = {0.f, 0.f, 0.f, 0.f};
        #pragma unroll
        for (int p = 0; p < 8; ++p) {
            float4 vp = *(const float4*)(vWp + (p << 11) + (ly << 8) + (lane << 2));
            vw.x += vp.x; vw.y += vp.y; vw.z += vp.z; vw.w += vp.w;
        }
        acc += (float)gv[0] * vw.x + (float)gv[1] * vw.y
             + (float)gv[2] * vw.z + (float)gv[3] * vw.w;
    }
    #pragma unroll
    for (int j = 0; j < 32; ++j) {
        int idx = lane + (j << 6);
        int ly = idx >> 8, c = idx & 255;
        acc += skip_b[(ly << 9) + 256 + c] * loc_W[c];
    }
    #pragma unroll
    for (int off = 32; off; off >>= 1) acc += __shfl_down(acc, off);
    if (lane == 0) {
        int l = o >> 4, b = o & 15;
        out[b * LOUT + l] = (acc + loc_b[0]) * proj_W[0] + proj_b[0];
    }
}

extern "C" void kernel_launch(void* const* d_in, const int* in_sizes, int n_in,
                              void* d_out, int out_size, void* d_ws, size_t ws_size,
                              hipStream_t stream)
{
    const float* x_lag  = (const float*)d_in[0];
    const float* x_cov  = (const float*)d_in[1];
    const float* up_W   = (const float*)d_in[2];
    const float* up_b   = (const float*)d_in[3];
    const float* dil_w  = (const float*)d_in[4];
    const float* dil_b  = (const float*)d_in[5];
    const float* skip_w = (const float*)d_in[6];
    const float* skip_b = (const float*)d_in[7];
    const float* loc_W  = (const float*)d_in[8];
    const float* loc_b  = (const float*)d_in[9];
    const float* proj_W = (const float*)d_in[10];
    const float* proj_b = (const float*)d_in[11];
    float* out = (float*)d_out;

    unsigned char* ws = (unsigned char*)d_ws;
    __bf16* hb    = (__bf16*)ws;                  // 2,883,584
    __bf16* gated = (__bf16*)(ws + 2883584);      // 2,883,584 (g for ly 0..4)
    __bf16* gA    = (__bf16*)(ws + 5767168);      // 2,359,296 (g5: 4608 rows)
    __bf16* gB    = (__bf16*)(ws + 8126464);      // 1,835,008 (g6: 3584 rows)
    __bf16* g7    = (__bf16*)(ws + 9961472);      // 786,432
    __bf16* gsave = (__bf16*)(ws + 10747904);     // 3,932,160 (5 slots)
    __bf16* wT    = (__bf16*)(ws + 14680064);     // 4,194,304
    __bf16* w2    = (__bf16*)(ws + 18874368);     // 655,360 (ly 0..4)
    __bf16* w2T   = (__bf16*)(ws + 19529728);     // 262,144 (ly 5,6)
    __bf16* V     = (__bf16*)(ws + 19791872);     // 1,572,864 (3 pairs)
    float*  vWp   = (float*)(ws + 21364736);      // 65,536
    float*  cbias = (float*)(ws + 21430272);      // 4,096

    hipLaunchKernelGGL(prep_up, dim3(2048), dim3(256), 0, stream,
                       dil_w, skip_w, x_lag, x_cov, up_W, up_b, loc_W,
                       wT, w2, w2T, hb, vWp);

    // D0: gate layer 0 + 3 V GEMMs + 2 cbias folds
    {
        int tb = T0 + 2, M = (T_TOTAL - tb) * NB;
        int mtp = (((M + 63) >> 6) + 7) & ~7;
        int ng0 = mtp * 8;
        hipLaunchKernelGGL(d0_kernel, dim3(ng0 + 384 + 128), dim3(512), 0, stream,
                           hb, gated, wT, dil_b, w2T, skip_b, V, cbias,
                           gsave, ng0, tb, M);
        hipLaunchKernelGGL(skip_h, dim3(ng0), dim3(512), 0, stream,
                           gated, w2, hb, skip_b, tb, M);
    }
    // layers 1..4: gate + skip
    for (int i = 1; i < 5; ++i) {
        int dil = 1 << i;
        int tb = T0 + 2 * dil;
        int M = (T_TOTAL - tb) * NB;
        int mtp = (((M + 63) >> 6) + 7) & ~7;
        hipLaunchKernelGGL(gate_n32, dim3(mtp * 8), dim3(512), 0, stream,
                           hb, gated, wT + ((size_t)i << 18),
                           dil_b + (i << 9),
                           gsave + (size_t)i * 1536 * 256, 1, tb, dil, M);
        hipLaunchKernelGGL(skip_h, dim3(mtp * 8), dim3(512), 0, stream,
                           gated, w2 + ((size_t)i << 16), hb,
                           skip_b + (i << 9), tb, M);
    }
    // layer 5: gate only -> gA (skip_5 eliminated by substitution)
    {
        int tb = T0 + 64, M = (T_TOTAL - tb) * NB;   // dil=32, M=4608
        int mtp = (((M + 63) >> 6) + 7) & ~7;
        hipLaunchKernelGGL(gate_n32, dim3(mtp * 8), dim3(512), 0, stream,
                           hb, gA, wT + ((size_t)5 << 18), dil_b + (5 << 9),
                           gsave, 0, tb, 32, M);
    }
    // layer 6 substituted: K=1024 [h5 taps | g5@V65 taps] -> gB
    {
        int M = 3584;
        int mtp = (((M + 63) >> 6) + 7) & ~7;        // 56
        hipLaunchKernelGGL((gate_sub<16, 1024, 2048, 0, 1024, 0, 0>),
                           dim3(mtp * 8), dim3(512), 0, stream,
                           hb, gA, gA, gB,
                           wT + ((size_t)6 << 18), V, V, cbias, M);
    }
    // layer 7 substituted: K=1536 [h5 | g5@V75 | g6@V76] -> g7
    {
        int M = 1536;
        int mtp = (((M + 63) >> 6) + 7) & ~7;        // 24
        hipLaunchKernelGGL((gate_sub<24, 2048, 4096, 1024, 3072, 0, 2048>),
                           dim3(mtp * 8), dim3(512), 0, stream,
                           hb, gA, gB, g7,
                           wT + ((size_t)7 << 18), V + (1 << 18), V + (2 << 18),
                           cbias + 512, M);
    }
    hipLaunchKernelGGL(final_v6, dim3(LOUT * NB / 4), dim3(256), 0, stream,
                       gsave, gA, gB, g7, vWp, skip_b,
                       loc_W, loc_b, proj_W, proj_b, out);
}

// Round 20
// 105.845 us; speedup vs baseline: 1.0845x; 1.0845x over previous
//
#include <hip/hip_runtime.h>
#include <math.h>
#include <stdint.h>

#define T_TOTAL 2048
#define NB 16
#define D 256
#define T0 1696      // h buffer covers t in [1696, 2047]
#define TBUF 352
#define TSKIP 1952   // output rows t in [1952, 2047]
#define LOUT 96

typedef __bf16 bf16x8 __attribute__((ext_vector_type(8)));
typedef __bf16 bf16x4v __attribute__((ext_vector_type(4)));
typedef float f32x4 __attribute__((ext_vector_type(4)));

__device__ __forceinline__ void gload_lds16(const void* src, void* lds_dst) {
    auto g = (const __attribute__((address_space(1))) void*)(uintptr_t)src;
    auto l = (__attribute__((address_space(3))) void*)(uintptr_t)(
                 (uint32_t)(uintptr_t)lds_dst);
    __builtin_amdgcn_global_load_lds(g, l, 16, 0, 0);
}

// XCD-grouped decode over ngate blocks (ngate = mtp*8, mtp%8==0)
__device__ __forceinline__ void decode_tile(int id, int ngate, int& rt, int& ct) {
    int k = id & 7;
    int j = id >> 3;
    int rpx = ngate >> 6;
    rt = k * rpx + (j >> 3);
    ct = j & 7;
}

// ---------------- prep: wT, w2(ly0-5), w2T(ly6), up-projection(bf16 h), vW partials
__global__ __launch_bounds__(256) void prep_up(
    const float* __restrict__ dil_w, const float* __restrict__ skip_w,
    const float* __restrict__ x_lag, const float* __restrict__ x_cov,
    const float* __restrict__ up_W, const float* __restrict__ up_b,
    const float* __restrict__ loc_W,
    __bf16* __restrict__ wT, __bf16* __restrict__ w2, __bf16* __restrict__ w2T,
    __bf16* __restrict__ hb, float* __restrict__ vWp)
{
    const int g0 = blockIdx.x * 256 + threadIdx.x;
    const int NT = 2048 * 256;

    // job A: dil_w transpose -> wT[i][co][k], k = tap*256+ci
    for (int u = g0; u < 8 * 512 * 32; u += NT) {
        int j = u & 31;
        int cog = u >> 5;
        const float* src = dil_w + ((size_t)cog << 9) + (j << 4);
        float4 a = *(const float4*)(src);
        float4 b = *(const float4*)(src + 4);
        float4 c = *(const float4*)(src + 8);
        float4 d = *(const float4*)(src + 12);
        bf16x8 t0 = {(__bf16)a.x, (__bf16)a.z, (__bf16)b.x, (__bf16)b.z,
                     (__bf16)c.x, (__bf16)c.z, (__bf16)d.x, (__bf16)d.z};
        bf16x8 t1 = {(__bf16)a.y, (__bf16)a.w, (__bf16)b.y, (__bf16)b.w,
                     (__bf16)c.y, (__bf16)c.w, (__bf16)d.y, (__bf16)d.w};
        *(bf16x8*)(wT + ((size_t)cog << 9) + (j << 3)) = t0;
        *(bf16x8*)(wT + ((size_t)cog << 9) + 256 + (j << 3)) = t1;
    }
    // job B1: skip_w h-half cast -> w2[ly][co][ci], ly 0..5
    for (int u = g0; u < 6 * 256 * 32; u += NT) {
        int row = u >> 5, j = u & 31;             // row = ly*256+co
        int ly = row >> 8, co = row & 255;
        const float* src = skip_w + (((size_t)(ly << 9) + co) << 8) + (j << 3);
        float4 a = *(const float4*)(src);
        float4 b = *(const float4*)(src + 4);
        bf16x8 v = {(__bf16)a.x, (__bf16)a.y, (__bf16)a.z, (__bf16)a.w,
                    (__bf16)b.x, (__bf16)b.y, (__bf16)b.z, (__bf16)b.w};
        *(bf16x8*)(w2 + ((size_t)row << 8) + (j << 3)) = v;
    }
    // job B2: skip_w h-half transpose, layer 6 -> w2T[ci][co]
    for (int u = g0; u < 256 * 32; u += NT) {
        int co = u >> 5, j = u & 31;
        const float* src = skip_w + (((size_t)(6 << 9) + co) << 8) + (j << 3);
        float4 a = *(const float4*)(src);
        float4 b = *(const float4*)(src + 4);
        float v[8] = {a.x, a.y, a.z, a.w, b.x, b.y, b.z, b.w};
        __bf16* wt = w2T + ((size_t)(j << 3) << 8) + co;
        #pragma unroll
        for (int e = 0; e < 8; ++e) wt[(size_t)e << 8] = (__bf16)v[e];
    }
    // job C: up-projection -> hb (bf16 accumulator master)
    for (int u = g0; u < TBUF * NB * D; u += NT) {
        int row = u >> 8, c = u & 255;
        int tt = row >> 4, b = row & 15, t = T0 + tt;
        float acc = up_b[c] + x_lag[t * NB + b] * up_W[c];
        const float* cov = &x_cov[(t * NB + b) * 7];
        #pragma unroll
        for (int j = 0; j < 7; ++j)
            acc += cov[j] * up_W[(j + 1) * D + c];
        hb[u] = (__bf16)acc;
    }
    // job D: vW partials over s-half skip_w (all 8 layers)
    for (int u = g0; u < 16384; u += NT) {
        int part = u >> 11;
        int r = u & 2047;
        int ly = r >> 8, ci = r & 255;
        const float* sw = skip_w + (((size_t)(ly << 9) + 256 + (part << 5)) << 8) + ci;
        float acc = 0.f;
        #pragma unroll 8
        for (int c = 0; c < 32; ++c)
            acc += sw[(size_t)c << 8] * loc_W[(part << 5) + c];
        vWp[u] = acc;
    }
}

// ---------------- D0: gate layer0 | V76 GEMM | cbias7 | vW reduce | sbc fold
__global__ __launch_bounds__(512, 4) void d0_kernel(
    const __bf16* __restrict__ hb, __bf16* __restrict__ gated,
    const __bf16* __restrict__ wT, const float* __restrict__ dil_b,
    const __bf16* __restrict__ w2T, const float* __restrict__ skip_b,
    const float* __restrict__ loc_W, const float* __restrict__ vWp,
    __bf16* __restrict__ V, float* __restrict__ cbias,
    float* __restrict__ vW, float* __restrict__ sbc,
    __bf16* __restrict__ gsv, int ngate, int tb, int M)
{
    __shared__ __align__(16) unsigned char lds[32768];
    const int id = blockIdx.x;
    const int tid = threadIdx.x;
    const int lane = tid & 63, wid = tid >> 6;
    const int wm = wid >> 1, wn = wid & 1;
    const int l15 = lane & 15, l4 = lane >> 4;
    const int ach = lane & 7;

    if (id < ngate) {
        // ---- gate layer 0 (K=512, dil=1), save tail to gsv
        int rt, ct;
        decode_tile(id, ngate, rt, ct);
        const int m0 = rt << 6;
        if (m0 >= M) return;
        const int cb = ct << 5;
        const int arow = (wid << 3) + (lane >> 3);
        const int aswz = (ach ^ (arow & 7)) << 3;
        const int bwid = wid & 3, bhalf = wid >> 2;
        const int brow = (bwid << 3) + (lane >> 3);
        const int bswz = (ach ^ (brow & 7)) << 3;
        const int roff1 = (tb - T0) * 16;
        const int roff0 = roff1 - 16;

        f32x4 accf = {}, accg = {};
        auto stage = [&](int t, int buf) {
            const int k0 = t << 6;
            const int ci0 = k0 & 255;
            const int roff = (t < 4) ? roff0 : roff1;
            unsigned char* base = lds + buf * 16384;
            int m = m0 + arow; if (m >= M) m = M - 1;
            gload_lds16(hb + (size_t)(m + roff) * 256 + ci0 + aswz,
                        base + (wid << 10));
            gload_lds16(wT + (size_t)(cb + bhalf * 256 + brow) * 512 + k0 + bswz,
                        base + 8192 + (bhalf << 12) + (bwid << 10));
        };
        stage(0, 0);
        for (int t = 0; t < 8; ++t) {
            const int buf = t & 1;
            if (t < 7) {
                stage(t + 1, buf ^ 1);
                asm volatile("s_waitcnt vmcnt(2)" ::: "memory");
            } else {
                asm volatile("s_waitcnt vmcnt(0)" ::: "memory");
            }
            __builtin_amdgcn_s_barrier();
            const unsigned char* base = lds + buf * 16384;
            __builtin_amdgcn_s_setprio(1);
            #pragma unroll
            for (int ks = 0; ks < 2; ++ks) {
                const int kb = (ks << 6) + (l4 << 4);
                int r = (wm << 4) + l15;
                bf16x8 av = *(const bf16x8*)(base + r * 128 + (kb ^ ((r & 7) << 4)));
                int n = (wn << 4) + l15;
                int o = n * 128 + (kb ^ ((n & 7) << 4));
                bf16x8 bfv = *(const bf16x8*)(base + 8192 + o);
                bf16x8 bgv = *(const bf16x8*)(base + 12288 + o);
                accf = __builtin_amdgcn_mfma_f32_16x16x32_bf16(av, bfv, accf, 0, 0, 0);
                accg = __builtin_amdgcn_mfma_f32_16x16x32_bf16(av, bgv, accg, 0, 0, 0);
            }
            __builtin_amdgcn_s_setprio(0);
            __builtin_amdgcn_s_barrier();
        }
        {
            const int ms0 = (TSKIP - tb) * 16;
            const int soff = (tb - TSKIP) * 16;
            int c = cb + (wn << 4) + l15;
            float bfb = dil_b[c], bgb = dil_b[c + 256];
            #pragma unroll
            for (int r = 0; r < 4; ++r) {
                int m = m0 + (wm << 4) + (l4 << 2) + r;
                if (m < M) {
                    float fv = accf[r] + bfb;
                    float gv = accg[r] + bgb;
                    float th = 2.0f / (1.0f + __expf(-2.0f * fv)) - 1.0f;
                    float sg = 1.0f / (1.0f + __expf(-gv));
                    __bf16 val = (__bf16)(th * sg);
                    gated[(size_t)m * 256 + c] = val;
                    if (m >= ms0)
                        gsv[(size_t)(m + soff) * 256 + c] = val;
                }
            }
        }
    } else if (id < ngate + 128) {
        // ---- V76 GEMM: V[n][a*256+ci] = sum_co wT7[n][a*256+co] * w2T6[ci][co]
        int v = id - ngate;
        int a = v >> 6;
        int r = v & 63;
        int rt = r >> 3, ct = r & 7;
        const int n0t = rt << 6;
        const int cb = ct << 5;
        const __bf16* Awt = wT + ((size_t)7 << 18) + (a << 8);
        const int arow = (wid << 3) + (lane >> 3);
        const int aswz = (ach ^ (arow & 7)) << 3;
        const int brow = (wid << 3) + (lane >> 3);
        const int bswz = (ach ^ (brow & 7)) << 3;

        f32x4 acc = {};
        auto stage = [&](int t, int buf) {
            const int k0 = t << 6;
            unsigned char* base = lds + buf * 12288;
            gload_lds16(Awt + (size_t)(n0t + arow) * 512 + k0 + aswz,
                        base + (wid << 10));
            if (wid < 4)
                gload_lds16(w2T + (size_t)(cb + brow) * 256 + k0 + bswz,
                            base + 8192 + (wid << 10));
        };
        stage(0, 0);
        for (int t = 0; t < 4; ++t) {
            const int buf = t & 1;
            if (t < 3) {
                stage(t + 1, buf ^ 1);
                if (wid < 4) { asm volatile("s_waitcnt vmcnt(2)" ::: "memory"); }
                else         { asm volatile("s_waitcnt vmcnt(1)" ::: "memory"); }
            } else {
                asm volatile("s_waitcnt vmcnt(0)" ::: "memory");
            }
            __builtin_amdgcn_s_barrier();
            const unsigned char* base = lds + buf * 12288;
            #pragma unroll
            for (int ks = 0; ks < 2; ++ks) {
                const int kb = (ks << 6) + (l4 << 4);
                int rr = (wm << 4) + l15;
                bf16x8 av = *(const bf16x8*)(base + rr * 128 + (kb ^ ((rr & 7) << 4)));
                int nn = (wn << 4) + l15;
                int o = nn * 128 + (kb ^ ((nn & 7) << 4));
                bf16x8 bv = *(const bf16x8*)(base + 8192 + o);
                acc = __builtin_amdgcn_mfma_f32_16x16x32_bf16(av, bv, acc, 0, 0, 0);
            }
            __builtin_amdgcn_s_barrier();
        }
        {
            int c = cb + (wn << 4) + l15;
            #pragma unroll
            for (int rr = 0; rr < 4; ++rr) {
                int n = n0t + (wm << 4) + (l4 << 2) + rr;
                V[(size_t)n * 512 + (a << 8) + c] = (__bf16)acc[rr];
            }
        }
    } else if (id < ngate + 192) {
        // ---- cbias7: cbias[n] = dil_b[7*512+n] + sum_k sb6_h[k&255]*wT7[n][k]
        int cblk = id - ngate - 128;              // 0..63
        int n = cblk * 8 + wid;                   // 0..511
        const __bf16* wrow = wT + ((size_t)7 << 18) + ((size_t)n << 9);
        float s = 0.f;
        #pragma unroll
        for (int e = 0; e < 8; ++e) {
            int k = (lane << 3) + e;
            s += skip_b[(6 << 9) + (k & 255)] * (float)wrow[k];
        }
        #pragma unroll
        for (int off = 32; off; off >>= 1) s += __shfl_down(s, off);
        if (lane == 0)
            cbias[n] = dil_b[(7 << 9) + n] + s;
    } else if (id < ngate + 196) {
        // ---- vW reduce: vW[idx] = sum_p vWp[p][idx]
        int idx = (id - ngate - 192) * 512 + tid; // 0..2047
        float s = 0.f;
        #pragma unroll
        for (int p = 0; p < 8; ++p) s += vWp[(p << 11) + idx];
        vW[idx] = s;
    } else {
        // ---- sbc: scalar fold of skip-bias through loc_W
        float s = 0.f;
        for (int j = tid; j < 2048; j += 512) {
            int ly = j >> 8, c = j & 255;
            s += skip_b[(ly << 9) + 256 + c] * loc_W[c];
        }
        float* red = (float*)lds;
        red[tid] = s;
        __syncthreads();
        for (int off = 256; off; off >>= 1) {
            if (tid < off) red[tid] += red[tid + off];
            __syncthreads();
        }
        if (tid == 0) sbc[0] = red[0];
    }
}

// ---------------- GEMM1 narrow (layers 1..6): grid mtp*8, BN=32
__global__ __launch_bounds__(512, 4) void gate_n32(
    const __bf16* __restrict__ hb, __bf16* __restrict__ gout,
    const __bf16* __restrict__ wTl, const float* __restrict__ gbias,
    __bf16* __restrict__ gsv, int do_save,
    int tb, int dil, int M)
{
    __shared__ __align__(16) unsigned char lds[32768];
    int rt, ct;
    decode_tile(blockIdx.x, gridDim.x, rt, ct);
    const int m0 = rt << 6;
    if (m0 >= M) return;
    const int cb = ct << 5;
    const int tid = threadIdx.x;
    const int lane = tid & 63, wid = tid >> 6;
    const int wm = wid >> 1, wn = wid & 1;
    const int l15 = lane & 15, l4 = lane >> 4;
    const int arow = (wid << 3) + (lane >> 3);
    const int ach = lane & 7;
    const int aswz = (ach ^ (arow & 7)) << 3;
    const int bwid = wid & 3, bhalf = wid >> 2;
    const int brow = (bwid << 3) + (lane >> 3);
    const int bswz = (ach ^ (brow & 7)) << 3;
    const int roff1 = (tb - T0) * 16;
    const int roff0 = roff1 - dil * 16;

    f32x4 accf = {}, accg = {};
    auto stage = [&](int t, int buf) {
        const int k0 = t << 6;
        const int ci0 = k0 & 255;
        const int roff = (t < 4) ? roff0 : roff1;
        unsigned char* base = lds + buf * 16384;
        int m = m0 + arow; if (m >= M) m = M - 1;
        gload_lds16(hb + (size_t)(m + roff) * 256 + ci0 + aswz,
                    base + (wid << 10));
        gload_lds16(wTl + (size_t)(cb + bhalf * 256 + brow) * 512 + k0 + bswz,
                    base + 8192 + (bhalf << 12) + (bwid << 10));
    };
    stage(0, 0);
    for (int t = 0; t < 8; ++t) {
        const int buf = t & 1;
        if (t < 7) {
            stage(t + 1, buf ^ 1);
            asm volatile("s_waitcnt vmcnt(2)" ::: "memory");
        } else {
            asm volatile("s_waitcnt vmcnt(0)" ::: "memory");
        }
        __builtin_amdgcn_s_barrier();
        const unsigned char* base = lds + buf * 16384;
        __builtin_amdgcn_s_setprio(1);
        #pragma unroll
        for (int ks = 0; ks < 2; ++ks) {
            const int kb = (ks << 6) + (l4 << 4);
            int r = (wm << 4) + l15;
            bf16x8 av = *(const bf16x8*)(base + r * 128 + (kb ^ ((r & 7) << 4)));
            int n = (wn << 4) + l15;
            int o = n * 128 + (kb ^ ((n & 7) << 4));
            bf16x8 bfv = *(const bf16x8*)(base + 8192 + o);
            bf16x8 bgv = *(const bf16x8*)(base + 12288 + o);
            accf = __builtin_amdgcn_mfma_f32_16x16x32_bf16(av, bfv, accf, 0, 0, 0);
            accg = __builtin_amdgcn_mfma_f32_16x16x32_bf16(av, bgv, accg, 0, 0, 0);
        }
        __builtin_amdgcn_s_setprio(0);
        __builtin_amdgcn_s_barrier();
    }
    {
        const int ms0 = (TSKIP - tb) * 16;
        const int soff = (tb - TSKIP) * 16;
        int c = cb + (wn << 4) + l15;
        float bfb = gbias[c], bgb = gbias[c + 256];
        #pragma unroll
        for (int r = 0; r < 4; ++r) {
            int m = m0 + (wm << 4) + (l4 << 2) + r;
            if (m < M) {
                float fv = accf[r] + bfb;
                float gv = accg[r] + bgb;
                float th = 2.0f / (1.0f + __expf(-2.0f * fv)) - 1.0f;
                float sg = 1.0f / (1.0f + __expf(-gv));
                __bf16 val = (__bf16)(th * sg);
                gout[(size_t)m * 256 + c] = val;
                if (do_save && m >= ms0)
                    gsv[(size_t)(m + soff) * 256 + c] = val;
            }
        }
    }
}

// ---------------- substituted gate 7: K=1024 [h6 taps | g6@V76 taps], unrolled
__global__ __launch_bounds__(512, 4) void gate7_sub(
    const __bf16* __restrict__ hb, const __bf16* __restrict__ g6,
    __bf16* __restrict__ g7,
    const __bf16* __restrict__ wT7, const __bf16* __restrict__ Vl,
    const float* __restrict__ cb7, int M)
{
    __shared__ __align__(16) unsigned char lds[32768];
    int rt, ct;
    decode_tile(blockIdx.x, gridDim.x, rt, ct);
    const int m0 = rt << 6;
    if (m0 >= M) return;
    const int cb = ct << 5;
    const int tid = threadIdx.x;
    const int lane = tid & 63, wid = tid >> 6;
    const int wm = wid >> 1, wn = wid & 1;
    const int l15 = lane & 15, l4 = lane >> 4;
    const int arow = (wid << 3) + (lane >> 3);
    const int ach = lane & 7;
    const int aswz = (ach ^ (arow & 7)) << 3;
    const int bwid = wid & 3, bhalf = wid >> 2;
    const int brow = (bwid << 3) + (lane >> 3);
    const int bswz = (ach ^ (brow & 7)) << 3;

    f32x4 accf = {}, accg = {};
    auto stage = [&](int t, int buf) {
        unsigned char* base = lds + buf * 16384;
        int m = m0 + arow; if (m >= M) m = M - 1;
        if (t < 8) {
            const int k0 = t << 6;
            const int roff = (t < 4) ? 2048 : 4096;     // h6 taps: t-128, t
            gload_lds16(hb + (size_t)(m + roff) * 256 + (k0 & 255) + aswz,
                        base + (wid << 10));
            gload_lds16(wT7 + (size_t)(cb + bhalf * 256 + brow) * 512 + k0 + bswz,
                        base + 8192 + (bhalf << 12) + (bwid << 10));
        } else {
            const int k0 = (t - 8) << 6;
            const int goff = (t < 12) ? 0 : 2048;       // g6 taps: t-128, t
            gload_lds16(g6 + (size_t)(m + goff) * 256 + (k0 & 255) + aswz,
                        base + (wid << 10));
            gload_lds16(Vl + (size_t)(cb + bhalf * 256 + brow) * 512 + k0 + bswz,
                        base + 8192 + (bhalf << 12) + (bwid << 10));
        }
    };
    stage(0, 0);
    #pragma unroll
    for (int t = 0; t < 16; ++t) {
        const int buf = t & 1;
        if (t < 15) {
            stage(t + 1, buf ^ 1);
            asm volatile("s_waitcnt vmcnt(2)" ::: "memory");
        } else {
            asm volatile("s_waitcnt vmcnt(0)" ::: "memory");
        }
        __builtin_amdgcn_s_barrier();
        const unsigned char* base = lds + buf * 16384;
        __builtin_amdgcn_s_setprio(1);
        #pragma unroll
        for (int ks = 0; ks < 2; ++ks) {
            const int kb = (ks << 6) + (l4 << 4);
            int r = (wm << 4) + l15;
            bf16x8 av = *(const bf16x8*)(base + r * 128 + (kb ^ ((r & 7) << 4)));
            int n = (wn << 4) + l15;
            int o = n * 128 + (kb ^ ((n & 7) << 4));
            bf16x8 bfv = *(const bf16x8*)(base + 8192 + o);
            bf16x8 bgv = *(const bf16x8*)(base + 12288 + o);
            accf = __builtin_amdgcn_mfma_f32_16x16x32_bf16(av, bfv, accf, 0, 0, 0);
            accg = __builtin_amdgcn_mfma_f32_16x16x32_bf16(av, bgv, accg, 0, 0, 0);
        }
        __builtin_amdgcn_s_setprio(0);
        __builtin_amdgcn_s_barrier();
    }
    {
        int c = cb + (wn << 4) + l15;
        float bfb = cb7[c], bgb = cb7[c + 256];
        #pragma unroll
        for (int r = 0; r < 4; ++r) {
            int m = m0 + (wm << 4) + (l4 << 2) + r;
            if (m < M) {
                float fv = accf[r] + bfb;
                float gv = accg[r] + bgb;
                float th = 2.0f / (1.0f + __expf(-2.0f * fv)) - 1.0f;
                float sg = 1.0f / (1.0f + __expf(-gv));
                g7[(size_t)m * 256 + c] = (__bf16)(th * sg);
            }
        }
    }
}

// ---------------- GEMM2 h-only (layers 0..5): bf16 in-place h accumulate
__global__ __launch_bounds__(512, 4) void skip_h(
    const __bf16* __restrict__ gated, const __bf16* __restrict__ w2l,
    __bf16* __restrict__ hb, const float* __restrict__ sbias, int tb, int M)
{
    __shared__ __align__(16) unsigned char lds[24576];
    int rt, ct;
    decode_tile(blockIdx.x, gridDim.x, rt, ct);
    const int m0 = rt << 6;
    if (m0 >= M) return;
    const int cb = ct << 5;
    const int tid = threadIdx.x;
    const int lane = tid & 63, wid = tid >> 6;
    const int wm = wid >> 1, wn = wid & 1;
    const int l15 = lane & 15, l4 = lane >> 4;
    const int arow = (wid << 3) + (lane >> 3);
    const int ach = lane & 7;
    const int aswz = (ach ^ (arow & 7)) << 3;
    const int brow = (wid << 3) + (lane >> 3);    // valid for wid<4
    const int bswz = (ach ^ (brow & 7)) << 3;
    const int roff1 = (tb - T0) * 16;

    f32x4 acch = {};
    auto stage = [&](int t, int buf) {
        const int k0 = t << 6;
        unsigned char* base = lds + buf * 12288;
        int m = m0 + arow; if (m >= M) m = M - 1;
        gload_lds16(gated + (size_t)m * 256 + k0 + aswz,
                    base + (wid << 10));
        if (wid < 4)
            gload_lds16(w2l + (size_t)(cb + brow) * 256 + k0 + bswz,
                        base + 8192 + (wid << 10));
    };
    stage(0, 0);
    for (int t = 0; t < 4; ++t) {
        const int buf = t & 1;
        if (t < 3) {
            stage(t + 1, buf ^ 1);
            if (wid < 4) { asm volatile("s_waitcnt vmcnt(2)" ::: "memory"); }
            else         { asm volatile("s_waitcnt vmcnt(1)" ::: "memory"); }
        } else {
            asm volatile("s_waitcnt vmcnt(0)" ::: "memory");
        }
        __builtin_amdgcn_s_barrier();
        const unsigned char* base = lds + buf * 12288;
        __builtin_amdgcn_s_setprio(1);
        #pragma unroll
        for (int ks = 0; ks < 2; ++ks) {
            const int kb = (ks << 6) + (l4 << 4);
            int r = (wm << 4) + l15;
            bf16x8 av = *(const bf16x8*)(base + r * 128 + (kb ^ ((r & 7) << 4)));
            int n = (wn << 4) + l15;
            int o = n * 128 + (kb ^ ((n & 7) << 4));
            bf16x8 bhv = *(const bf16x8*)(base + 8192 + o);
            acch = __builtin_amdgcn_mfma_f32_16x16x32_bf16(av, bhv, acch, 0, 0, 0);
        }
        __builtin_amdgcn_s_setprio(0);
        __builtin_amdgcn_s_barrier();
    }
    {
        int c = cb + (wn << 4) + l15;
        float bhb = sbias[c];
        #pragma unroll
        for (int r = 0; r < 4; ++r) {
            int m = m0 + (wm << 4) + (l4 << 2) + r;
            if (m < M) {
                size_t hi = (size_t)(m + roff1) * 256 + c;
                float hv = (float)hb[hi] + acch[r] + bhb;
                hb[hi] = (__bf16)hv;
            }
        }
    }
}

// ---------------- final: out = (sum_l g_l . vW_l + sbc + loc_b)*projW + proj_b
__global__ __launch_bounds__(256) void final_v7(
    const __bf16* __restrict__ gsave, const __bf16* __restrict__ gated,
    const __bf16* __restrict__ g7,
    const float* __restrict__ vW, const float* __restrict__ sbc,
    const float* __restrict__ loc_b,
    const float* __restrict__ proj_W, const float* __restrict__ proj_b,
    float* __restrict__ out)
{
    int tid = threadIdx.x;
    int wid = tid >> 6, lane = tid & 63;
    int o = blockIdx.x * 4 + wid;        // o = (t - TSKIP)*16 + b
    const __bf16* bases[8] = {
        gsave,                  gsave + 1536 * 256,     gsave + 2 * 1536 * 256,
        gsave + 3 * 1536 * 256, gsave + 4 * 1536 * 256, gsave + 5 * 1536 * 256,
        gated + 2048 * 256,     g7 };
    float acc = 0.f;
    #pragma unroll
    for (int ly = 0; ly < 8; ++ly) {
        bf16x4v gv = *(const bf16x4v*)(bases[ly] + ((size_t)o << 8) + (lane << 2));
        float4 vw = *(const float4*)(vW + (ly << 8) + (lane << 2));
        acc += (float)gv[0] * vw.x + (float)gv[1] * vw.y
             + (float)gv[2] * vw.z + (float)gv[3] * vw.w;
    }
    #pragma unroll
    for (int off = 32; off; off >>= 1) acc += __shfl_down(acc, off);
    if (lane == 0) {
        int l = o >> 4, b = o & 15;
        out[b * LOUT + l] = (acc + sbc[0] + loc_b[0]) * proj_W[0] + proj_b[0];
    }
}

extern "C" void kernel_launch(void* const* d_in, const int* in_sizes, int n_in,
                              void* d_out, int out_size, void* d_ws, size_t ws_size,
                              hipStream_t stream)
{
    const float* x_lag  = (const float*)d_in[0];
    const float* x_cov  = (const float*)d_in[1];
    const float* up_W   = (const float*)d_in[2];
    const float* up_b   = (const float*)d_in[3];
    const float* dil_w  = (const float*)d_in[4];
    const float* dil_b  = (const float*)d_in[5];
    const float* skip_w = (const float*)d_in[6];
    const float* skip_b = (const float*)d_in[7];
    const float* loc_W  = (const float*)d_in[8];
    const float* loc_b  = (const float*)d_in[9];
    const float* proj_W = (const float*)d_in[10];
    const float* proj_b = (const float*)d_in[11];
    float* out = (float*)d_out;

    unsigned char* ws = (unsigned char*)d_ws;
    __bf16* hb    = (__bf16*)ws;                  // 2,883,584
    __bf16* gated = (__bf16*)(ws + 2883584);      // 2,883,584
    __bf16* g7    = (__bf16*)(ws + 5767168);      // 786,432
    __bf16* gsave = (__bf16*)(ws + 6553600);      // 4,718,592 (6 slots)
    __bf16* wT    = (__bf16*)(ws + 11272192);     // 4,194,304
    __bf16* w2    = (__bf16*)(ws + 15466496);     // 786,432 (ly 0..5)
    __bf16* w2T   = (__bf16*)(ws + 16252928);     // 131,072 (ly 6)
    __bf16* V     = (__bf16*)(ws + 16384000);     // 524,288
    float*  vWp   = (float*)(ws + 16908288);      // 65,536
    float*  cbias = (float*)(ws + 16973824);      // 2,048
    float*  vW    = (float*)(ws + 16975872);      // 8,192
    float*  sbc   = (float*)(ws + 16984064);      // 4

    hipLaunchKernelGGL(prep_up, dim3(2048), dim3(256), 0, stream,
                       dil_w, skip_w, x_lag, x_cov, up_W, up_b, loc_W,
                       wT, w2, w2T, hb, vWp);

    // D0: gate layer 0 + V76 GEMM + cbias7 + vW reduce + sbc
    {
        int tb = T0 + 2, M = (T_TOTAL - tb) * NB;
        int mtp = (((M + 63) >> 6) + 7) & ~7;
        int ng0 = mtp * 8;
        hipLaunchKernelGGL(d0_kernel, dim3(ng0 + 197), dim3(512), 0, stream,
                           hb, gated, wT, dil_b, w2T, skip_b, loc_W, vWp,
                           V, cbias, vW, sbc, gsave, ng0, tb, M);
        hipLaunchKernelGGL(skip_h, dim3(ng0), dim3(512), 0, stream,
                           gated, w2, hb, skip_b, tb, M);
    }
    // layers 1..5: gate + skip
    for (int i = 1; i < 6; ++i) {
        int dil = 1 << i;
        int tb = T0 + 2 * dil;
        int M = (T_TOTAL - tb) * NB;
        int mtp = (((M + 63) >> 6) + 7) & ~7;
        hipLaunchKernelGGL(gate_n32, dim3(mtp * 8), dim3(512), 0, stream,
                           hb, gated, wT + ((size_t)i << 18),
                           dil_b + (i << 9),
                           gsave + (size_t)i * 1536 * 256, 1, tb, dil, M);
        hipLaunchKernelGGL(skip_h, dim3(mtp * 8), dim3(512), 0, stream,
                           gated, w2 + ((size_t)i << 16), hb,
                           skip_b + (i << 9), tb, M);
    }
    // layer 6 gate (normal); output stays in `gated` for gate7_sub + final
    {
        int tb = T0 + 128, M = (T_TOTAL - tb) * NB;   // dil=64, M=3584
        int mtp = (((M + 63) >> 6) + 7) & ~7;
        hipLaunchKernelGGL(gate_n32, dim3(mtp * 8), dim3(512), 0, stream,
                           hb, gated, wT + ((size_t)6 << 18), dil_b + (6 << 9),
                           gsave, 0, tb, 64, M);
    }
    // layer 7 substituted: K=1024 [h6 taps | g6@V76 taps] -> g7
    {
        int M = 1536;
        int mtp = (((M + 63) >> 6) + 7) & ~7;         // 24
        hipLaunchKernelGGL(gate7_sub, dim3(mtp * 8), dim3(512), 0, stream,
                           hb, gated, g7, wT + ((size_t)7 << 18), V, cbias, M);
    }
    hipLaunchKernelGGL(final_v7, dim3(LOUT * NB / 4), dim3(256), 0, stream,
                       gsave, gated, g7, vW, sbc,
                       loc_b, proj_W, proj_b, out);
}